// Round 9
// baseline (100.182 us; speedup 1.0000x reference)
//
#include <hip/hip_runtime.h>
#include <math.h>

// Problem constants (reference: B=4, N=M=8192, D=3, fp32)
#define BQ      4
#define NPTS    8192
#define TOTALA  (2 * BQ * NPTS)    // 65536 (batch*dir rows)
#define MCHUNK  512                // m-points staged in LDS per block
#define NCH     (NPTS / MCHUNK)    // 16 m-chunks
#define NBLK    512                // n-points per block (4 waves x 128)

// ws offsets: part = float[NCH][TOTALA] = 4 MB; scr after it.
#define OFF_PART 0u
#define OFF_SCR  (4u << 20)

typedef __attribute__((ext_vector_type(8)))  short bf16x8;
typedef __attribute__((ext_vector_type(16))) float f32x16;

__device__ inline unsigned short f2bf(float f) {   // RNE float->bf16
  unsigned u = __float_as_uint(f);
  u += 0x7FFF + ((u >> 16) & 1);
  return (unsigned short)(u >> 16);
}
__device__ inline float bf2f(unsigned short h) {
  return __uint_as_float(((unsigned)h) << 16);
}
__device__ inline uint4 pack8(const unsigned short* e) {
  uint4 r;
  r.x = e[0] | ((unsigned)e[1] << 16);
  r.y = e[2] | ((unsigned)e[3] << 16);
  r.z = e[4] | ((unsigned)e[5] << 16);
  r.w = e[6] | ((unsigned)e[7] << 16);
  return r;
}

// Split-bf16 K=16 vectors: dot(Avec,Bvec) = ||a||^2+||b||^2-2a.b + O(2^-18)
// A = [ahi3, ahi3, alo3, sqa_hi, sqa_lo, 1, 1, 0,0,0]
// B = [-2bhi3, -2blo3, -2bhi3, 1, 1, sqb_hi, sqb_lo, 0,0,0]
__device__ inline void build_a(const float* p, uint4& lo, uint4& hi) {
  const float x = p[0], yv = p[1], z = p[2];
  const unsigned short xh = f2bf(x), yh = f2bf(yv), zh = f2bf(z);
  const unsigned short xl = f2bf(x - bf2f(xh));
  const unsigned short yl = f2bf(yv - bf2f(yh));
  const unsigned short zl = f2bf(z - bf2f(zh));
  const float sq = fmaf(x, x, fmaf(yv, yv, z * z));
  const unsigned short sh = f2bf(sq), sl = f2bf(sq - bf2f(sh));
  const unsigned short ONE = 0x3F80;
  const unsigned short av[16] = {xh, yh, zh, xh, yh, zh, xl, yl, zl,
                                 sh, sl, ONE, ONE, 0, 0, 0};
  lo = pack8(av);
  hi = pack8(av + 8);
}
__device__ inline void build_b(const float* p, uint4& lo, uint4& hi) {
  const float x = p[0], yv = p[1], z = p[2];
  const unsigned short xh = f2bf(x), yh = f2bf(yv), zh = f2bf(z);
  const unsigned short xl = f2bf(x - bf2f(xh));
  const unsigned short yl = f2bf(yv - bf2f(yh));
  const unsigned short zl = f2bf(z - bf2f(zh));
  const float sq = fmaf(x, x, fmaf(yv, yv, z * z));
  const unsigned short sh = f2bf(sq), sl = f2bf(sq - bf2f(sh));
  const unsigned short nxh = f2bf(-2.f * bf2f(xh)), nyh = f2bf(-2.f * bf2f(yh)),
                       nzh = f2bf(-2.f * bf2f(zh));
  const unsigned short nxl = f2bf(-2.f * bf2f(xl)), nyl = f2bf(-2.f * bf2f(yl)),
                       nzl = f2bf(-2.f * bf2f(zl));
  const unsigned short ONE = 0x3F80;
  const unsigned short bv[16] = {nxh, nyh, nzh, nxl, nyl, nzl, nxh, nyh, nzh,
                                 ONE, ONE, sh, sl, 0, 0, 0};
  lo = pack8(bv);
  hi = pack8(bv + 8);
}

// Transposed MFMA: mfma(b_lds, a_reg) -> reg-rows = m, lane-cols = n.
// Per wave: 4 a-frags (128 n-points); per t-tile: 1 ds_read_b128 feeds
// 4 MFMAs; 4 parallel 8-deep v_min3 folds. Frags built on the fly (no
// prep kernel). C/D rows (r&3)+8*(r>>2)+4*h; shfl_xor(32) merges halves.
__global__ __launch_bounds__(256, 4) void chamfer_min_kernel(
    const float* __restrict__ yhat, const float* __restrict__ y,
    unsigned char* __restrict__ ws) {
  if (blockIdx.x == 0 && blockIdx.y == 0 && blockIdx.z == 0 && threadIdx.x == 0) {
    float* scr = (float*)(ws + OFF_SCR);
    scr[0] = 0.f;
    ((unsigned*)scr)[1] = 0u;
  }
  const int bz = blockIdx.z, b = bz >> 1, dir = bz & 1;
  const float* A  = (dir ? y    : yhat) + (size_t)b * NPTS * 3;
  const float* Bp = (dir ? yhat : y   ) + (size_t)b * NPTS * 3;
  float* part = (float*)(ws + OFF_PART);

  __shared__ uint4 bs[2][MCHUNK];  // [k-half][point], 16 KB
  const int m0 = blockIdx.y * MCHUNK;
  for (int i = threadIdx.x; i < MCHUNK; i += 256) {
    uint4 lo, hi;
    build_b(Bp + (size_t)(m0 + i) * 3, lo, hi);
    bs[0][i] = lo;
    bs[1][i] = hi;
  }

  const int lane = threadIdx.x & 63, wave = threadIdx.x >> 6;
  const int h = lane >> 5, c = lane & 31;
  const int n0 = blockIdx.x * NBLK + wave * 128;
  bf16x8 af0, af1, af2, af3;
  {
    uint4 lo, hi;
    build_a(A + (size_t)(n0 + c) * 3, lo, hi);
    af0 = __builtin_bit_cast(bf16x8, h ? hi : lo);
    build_a(A + (size_t)(n0 + 32 + c) * 3, lo, hi);
    af1 = __builtin_bit_cast(bf16x8, h ? hi : lo);
    build_a(A + (size_t)(n0 + 64 + c) * 3, lo, hi);
    af2 = __builtin_bit_cast(bf16x8, h ? hi : lo);
    build_a(A + (size_t)(n0 + 96 + c) * 3, lo, hi);
    af3 = __builtin_bit_cast(bf16x8, h ? hi : lo);
  }
  __syncthreads();

  float rm0 = 3.0e38f, rm1 = 3.0e38f, rm2 = 3.0e38f, rm3 = 3.0e38f;
  const f32x16 z = (f32x16)(0.0f);

  for (int t = 0; t < MCHUNK / 32; ++t) {
    const bf16x8 bfr = __builtin_bit_cast(bf16x8, bs[h][t * 32 + c]);
    f32x16 p0 = __builtin_amdgcn_mfma_f32_32x32x16_bf16(bfr, af0, z, 0, 0, 0);
    f32x16 p1 = __builtin_amdgcn_mfma_f32_32x32x16_bf16(bfr, af1, z, 0, 0, 0);
    f32x16 p2 = __builtin_amdgcn_mfma_f32_32x32x16_bf16(bfr, af2, z, 0, 0, 0);
    f32x16 p3 = __builtin_amdgcn_mfma_f32_32x32x16_bf16(bfr, af3, z, 0, 0, 0);
#pragma unroll
    for (int r = 0; r < 16; r += 2) {      // 4 parallel 8-deep chains
      rm0 = fminf(rm0, fminf(p0[r], p0[r + 1]));  // v_min3_f32
      rm1 = fminf(rm1, fminf(p1[r], p1[r + 1]));
      rm2 = fminf(rm2, fminf(p2[r], p2[r + 1]));
      rm3 = fminf(rm3, fminf(p3[r], p3[r + 1]));
    }
  }

  // merge row-halves (h=0 rows {0-3,8-11,...}, h=1 rows {4-7,12-15,...})
  rm0 = fminf(rm0, __shfl_xor(rm0, 32));
  rm1 = fminf(rm1, __shfl_xor(rm1, 32));
  rm2 = fminf(rm2, __shfl_xor(rm2, 32));
  rm3 = fminf(rm3, __shfl_xor(rm3, 32));

  float* outp = part + (size_t)blockIdx.y * TOTALA + bz * NPTS + n0;
  if (h == 0) {
    outp[c] = rm0;
    outp[32 + c] = rm1;
  } else {
    outp[64 + c] = rm2;
    outp[96 + c] = rm3;
  }
}

// min across the 16 chunk-slices (rotated order to spread the 256 KB
// power-of-2 stride), clamp, sum -> atomicAdd -> last block sqrt+store.
__global__ __launch_bounds__(256) void chamfer_reduce_kernel(
    unsigned char* __restrict__ ws, float* __restrict__ out) {
  const float* part = (const float*)(ws + OFF_PART);
  float* scr = (float*)(ws + OFF_SCR);
  const int j = blockIdx.x * 256 + threadIdx.x;  // 0..65535
  const int wave = threadIdx.x >> 6, lane = threadIdx.x & 63;
  const int rot = (blockIdx.x * 4 + wave) & (NCH - 1);
  float mv = 3.4e38f;
#pragma unroll
  for (int cc = 0; cc < NCH; ++cc) {
    const int mc = (cc + rot) & (NCH - 1);
    mv = fminf(mv, part[(size_t)mc * TOTALA + j]);
  }
  float s = fmaxf(mv, 0.f);
#pragma unroll
  for (int off = 32; off > 0; off >>= 1) s += __shfl_down(s, off, 64);
  __shared__ float p4[4];
  if (lane == 0) p4[wave] = s;
  __syncthreads();
  if (threadIdx.x == 0) {
    atomicAdd(&scr[0], p4[0] + p4[1] + p4[2] + p4[3]);
    __threadfence();
    const unsigned ticket = atomicAdd(&((unsigned*)scr)[1], 1u);
    if (ticket == gridDim.x - 1) {
      __threadfence();
      const float total = atomicAdd(&scr[0], 0.f);  // atomic read
      out[0] = sqrtf(total * (1.0f / (float)TOTALA));
    }
  }
}

extern "C" void kernel_launch(void* const* d_in, const int* in_sizes, int n_in,
                              void* d_out, int out_size, void* d_ws, size_t ws_size,
                              hipStream_t stream) {
  const float* yhat = (const float*)d_in[0];
  const float* y    = (const float*)d_in[1];
  unsigned char* ws = (unsigned char*)d_ws;

  dim3 grid(NPTS / NBLK, NCH, 2 * BQ);  // 16 x 16 x 8 = 2048 blocks
  chamfer_min_kernel<<<grid, 256, 0, stream>>>(yhat, y, ws);
  chamfer_reduce_kernel<<<256, 256, 0, stream>>>(ws, (float*)d_out);
}